// Round 1
// baseline (694.776 us; speedup 1.0000x reference)
//
#include <hip/hip_runtime.h>

// MultilevelROIAligner: feats [8,{256,128,64,32}^2,256] fp32, boxes [8,256,4],
// out [8,256,7,7,256] fp32.
//
// One 64-thread block per (b, n, p, q). Box/level/grid math is wave-uniform;
// each lane loads 4 channels (float4) from the 4 bilinear corner rows
// (coalesced 1 KB per wave per corner) and writes 1 float4.

#define CROPS 7
#define NCH   256   // channels
#define NBOX  256   // boxes per batch

__global__ __launch_bounds__(64)
void roi_align_kernel(const float* __restrict__ f2,
                      const float* __restrict__ f3,
                      const float* __restrict__ f4,
                      const float* __restrict__ f5,
                      const float* __restrict__ boxes,
                      float* __restrict__ out)
{
    const int blk = blockIdx.x;          // (b*NBOX + n)*49 + p*7 + q
    const int pq  = blk % 49;
    const int bn  = blk / 49;
    const int p   = pq / 7;
    const int q   = pq - p * 7;
    const int b   = bn >> 8;             // NBOX == 256

    // ---- box (uniform across wave -> scalar loads) ----
    const float* bx = boxes + (size_t)bn * 4;
    const float by1 = bx[0], bx1 = bx[1], by2 = bx[2], bx2 = bx[3];
    float bh = by2 - by1;
    float bw = bx2 - bx1;

    // level assignment: floor(log2(sqrt(h*w)/224)) + 4, clipped to [2,5]
    const float as   = sqrtf(bh * bw);
    float levf = floorf(log2f(as / 224.0f)) + 4.0f;
    levf = fminf(fmaxf(levf, 2.0f), 5.0f);
    const int   lev   = (int)levf;
    const float scale = exp2f(levf);     // exact power of two

    const float y0b = by1 / scale;
    const float x0b = bx1 / scale;
    const float bhp = bh / scale;
    const float bwp = bw / scale;

    const int   lev0 = lev - 2;
    const int   W    = 256 >> lev0;      // level is square: H == W
    const float bnd  = (float)(W - 1);   // bnd_y == bnd_x

    // ---- compute_grid_positions for this (p, q) ----
    const float gy = y0b + ((float)p + 0.5f) * bhp / 7.0f;
    const float gx = x0b + ((float)q + 0.5f) * bwp / 7.0f;

    const float fy0 = fminf(fmaxf(floorf(gy), 0.0f), bnd);
    const float fy1 = fminf(fy0 + 1.0f, bnd);
    const float fx0 = fminf(fmaxf(floorf(gx), 0.0f), bnd);
    const float fx1 = fminf(fx0 + 1.0f, bnd);

    const float ly = gy - fy0;
    const float lx = gx - fx0;
    const float ky0 = 1.0f - ly, ky1 = ly;
    const float kx0 = 1.0f - lx, kx1 = lx;

    const int yi0 = (int)fy0, yi1 = (int)fy1;
    const int xi0 = (int)fx0, xi1 = (int)fx1;

    // ---- level base pointer (uniform branch) ----
    const float* base;
    if      (lev0 == 0) base = f2 + (size_t)b * (256u * 256u * NCH);
    else if (lev0 == 1) base = f3 + (size_t)b * (128u * 128u * NCH);
    else if (lev0 == 2) base = f4 + (size_t)b * ( 64u *  64u * NCH);
    else                base = f5 + (size_t)b * ( 32u *  32u * NCH);

    const int t = threadIdx.x;           // lane -> 4 channels via float4

    const float4* r00 = (const float4*)(base + ((size_t)yi0 * W + xi0) * NCH) + t;
    const float4* r01 = (const float4*)(base + ((size_t)yi0 * W + xi1) * NCH) + t;
    const float4* r10 = (const float4*)(base + ((size_t)yi1 * W + xi0) * NCH) + t;
    const float4* r11 = (const float4*)(base + ((size_t)yi1 * W + xi1) * NCH) + t;

    const float4 v00 = *r00;
    const float4 v01 = *r01;
    const float4 v10 = *r10;
    const float4 v11 = *r11;

    const float w00 = ky0 * kx0;
    const float w01 = ky0 * kx1;
    const float w10 = ky1 * kx0;
    const float w11 = ky1 * kx1;

    float4 o;
    o.x = v00.x * w00 + v01.x * w01 + v10.x * w10 + v11.x * w11;
    o.y = v00.y * w00 + v01.y * w01 + v10.y * w10 + v11.y * w11;
    o.z = v00.z * w00 + v01.z * w01 + v10.z * w10 + v11.z * w11;
    o.w = v00.w * w00 + v01.w * w01 + v10.w * w10 + v11.w * w11;

    float4* op = (float4*)(out + (size_t)blk * NCH) + t;
    *op = o;
}

extern "C" void kernel_launch(void* const* d_in, const int* in_sizes, int n_in,
                              void* d_out, int out_size, void* d_ws, size_t ws_size,
                              hipStream_t stream) {
    const float* f2    = (const float*)d_in[0];
    const float* f3    = (const float*)d_in[1];
    const float* f4    = (const float*)d_in[2];
    const float* f5    = (const float*)d_in[3];
    const float* boxes = (const float*)d_in[4];
    float* out = (float*)d_out;

    const int nblocks = 8 * NBOX * 49;   // B * N * CROP*CROP = 100352
    roi_align_kernel<<<nblocks, 64, 0, stream>>>(f2, f3, f4, f5, boxes, out);
}